// Round 1
// baseline (3652.716 us; speedup 1.0000x reference)
//
#include <hip/hip_runtime.h>

#define N_NODES 100000
#define BM 64
#define BN 64
#define BK 32

// ---------------- degree / norm kernels ----------------

__global__ void deg_kernel(const int* __restrict__ src, const int* __restrict__ dst,
                           float* __restrict__ odeg, float* __restrict__ ideg, int E) {
    int e = blockIdx.x * blockDim.x + threadIdx.x;
    if (e < E) {
        atomicAdd(&odeg[src[e]], 1.0f);
        atomicAdd(&ideg[dst[e]], 1.0f);
    }
}

__global__ void rsqrt_kernel(float* __restrict__ a, float* __restrict__ b, int n) {
    int i = blockIdx.x * blockDim.x + threadIdx.x;
    if (i < n) {
        a[i] = rsqrtf(fmaxf(a[i], 1.0f));
        b[i] = rsqrtf(fmaxf(b[i], 1.0f));
    }
}

// ---------------- edge aggregation (scatter-add) ----------------
// out[dst[e], :] += x[src[e], :] * (scale ? scale[src[e]] : 1)
// One thread per (edge, float4-chunk).

template <int F>
__global__ void agg_kernel(const float* __restrict__ x, const float* __restrict__ scale,
                           const int* __restrict__ src, const int* __restrict__ dst,
                           float* __restrict__ out, int E) {
    constexpr int V = F / 4;
    long long t = (long long)blockIdx.x * blockDim.x + threadIdx.x;
    int e = (int)(t / V);
    int v = (int)(t % V);
    if (e >= E) return;
    int s = src[e];
    int d = dst[e];
    float4 val = ((const float4*)x)[(long long)s * V + v];
    if (scale) {
        float sc = scale[s];
        val.x *= sc; val.y *= sc; val.z *= sc; val.w *= sc;
    }
    float* o = out + (long long)d * F + v * 4;
    atomicAdd(o + 0, val.x);
    atomicAdd(o + 1, val.y);
    atomicAdd(o + 2, val.z);
    atomicAdd(o + 3, val.w);
}

// ---------------- pointwise: y = (relu?)(y * s[row] + bias[col]) ----------------

template <int F>
__global__ void scale_bias_kernel(float* __restrict__ y, const float* __restrict__ s,
                                  const float* __restrict__ bias, int doRelu) {
    constexpr int V = F / 4;
    long long t = (long long)blockIdx.x * blockDim.x + threadIdx.x;
    int n = (int)(t / V);
    int v = (int)(t % V);
    if (n >= N_NODES) return;
    float4 val = ((float4*)y)[(long long)n * V + v];
    float sc = s[n];
    float4 b = ((const float4*)bias)[v];
    val.x = val.x * sc + b.x;
    val.y = val.y * sc + b.y;
    val.z = val.z * sc + b.z;
    val.w = val.w * sc + b.w;
    if (doRelu) {
        val.x = fmaxf(val.x, 0.0f);
        val.y = fmaxf(val.y, 0.0f);
        val.z = fmaxf(val.z, 0.0f);
        val.w = fmaxf(val.w, 0.0f);
    }
    ((float4*)y)[(long long)n * V + v] = val;
}

// ---------------- fp32 tiled GEMM ----------------
// C[M,N] = (preScale ? diag(preScale) : I) * A[M,K] @ B[K,N], then
// epilogue: * postScale[row] + bias[col], optional relu.
// 256 threads, 64x64 tile, 4x4 per thread, both LDS fragments read as b128.

__global__ __launch_bounds__(256) void sgemm_kernel(
    const float* __restrict__ A, const float* __restrict__ B, float* __restrict__ C,
    int M, int N, int K,
    const float* __restrict__ preScale, const float* __restrict__ postScale,
    const float* __restrict__ bias, int doRelu) {
    __shared__ float As[BK][BM + 4];  // transposed A tile; +4 keeps 16B alignment
    __shared__ float Bs[BK][BN + 4];

    const int tid = threadIdx.x;
    const int tx = tid & 15;
    const int ty = tid >> 4;
    const int rowBase = blockIdx.y * BM;
    const int colBase = blockIdx.x * BN;

    float acc[4][4] = {{0.0f}};

    for (int k0 = 0; k0 < K; k0 += BK) {
        // Load A tile (64 rows x 32 cols), store transposed into As[k][m].
#pragma unroll
        for (int i = 0; i < 2; ++i) {
            int idx = tid + i * 256;  // 0..511 = 64 rows x 8 float4
            int r = idx >> 3;
            int c4 = idx & 7;
            int gr = rowBase + r;
            float4 v = make_float4(0.f, 0.f, 0.f, 0.f);
            if (gr < M) {
                v = *(const float4*)(A + (size_t)gr * K + k0 + c4 * 4);
                if (preScale) {
                    float s = preScale[gr];
                    v.x *= s; v.y *= s; v.z *= s; v.w *= s;
                }
            }
            As[c4 * 4 + 0][r] = v.x;
            As[c4 * 4 + 1][r] = v.y;
            As[c4 * 4 + 2][r] = v.z;
            As[c4 * 4 + 3][r] = v.w;
        }
        // Load B tile (32 rows x 64 cols).
#pragma unroll
        for (int i = 0; i < 2; ++i) {
            int idx = tid + i * 256;  // 0..511 = 32 rows x 16 float4
            int r = idx >> 4;
            int c4 = idx & 15;
            int gc = colBase + c4 * 4;
            float4 v = make_float4(0.f, 0.f, 0.f, 0.f);
            if (gc < N) v = *(const float4*)(B + (size_t)(k0 + r) * N + gc);
            *(float4*)&Bs[r][c4 * 4] = v;
        }
        __syncthreads();
#pragma unroll
        for (int k = 0; k < BK; ++k) {
            float4 av = *(const float4*)&As[k][ty * 4];
            float4 bv = *(const float4*)&Bs[k][tx * 4];
            float a[4] = {av.x, av.y, av.z, av.w};
            float b[4] = {bv.x, bv.y, bv.z, bv.w};
#pragma unroll
            for (int i = 0; i < 4; ++i)
#pragma unroll
                for (int j = 0; j < 4; ++j)
                    acc[i][j] = fmaf(a[i], b[j], acc[i][j]);
        }
        __syncthreads();
    }

    int gc = colBase + tx * 4;
    if (gc >= N) return;
#pragma unroll
    for (int i = 0; i < 4; ++i) {
        int gr = rowBase + ty * 4 + i;
        if (gr >= M) continue;
        float ps = postScale ? postScale[gr] : 1.0f;
        float4 o;
        o.x = acc[i][0] * ps;
        o.y = acc[i][1] * ps;
        o.z = acc[i][2] * ps;
        o.w = acc[i][3] * ps;
        if (bias) {
            o.x += bias[gc + 0];
            o.y += bias[gc + 1];
            o.z += bias[gc + 2];
            o.w += bias[gc + 3];
        }
        if (doRelu) {
            o.x = fmaxf(o.x, 0.0f);
            o.y = fmaxf(o.y, 0.0f);
            o.z = fmaxf(o.z, 0.0f);
            o.w = fmaxf(o.w, 0.0f);
        }
        *(float4*)(C + (size_t)gr * N + gc) = o;
    }
}

// ---------------- launch ----------------

extern "C" void kernel_launch(void* const* d_in, const int* in_sizes, int n_in,
                              void* d_out, int out_size, void* d_ws, size_t ws_size,
                              hipStream_t stream) {
    const float* x  = (const float*)d_in[0];
    const int* src  = (const int*)d_in[1];
    const int* dst  = (const int*)d_in[2];
    const float* W1 = (const float*)d_in[3];
    const float* b1 = (const float*)d_in[4];
    const float* W2 = (const float*)d_in[5];
    const float* b2 = (const float*)d_in[6];
    const float* W3 = (const float*)d_in[7];
    const float* b3 = (const float*)d_in[8];
    float* out = (float*)d_out;
    const int E = in_sizes[1];

    char* ws = (char*)d_ws;
    float* inv_out = (float*)ws;                      // 100000 f32
    float* inv_in  = (float*)(ws + 400000);           // 100000 f32
    float* bufA    = (float*)(ws + 800000);           // 100000*128 f32 (51.2 MB)
    float* bufB    = (float*)(ws + 52000000);         // 100000*256 f32 (102.4 MB)

    // degrees -> inv sqrt norms
    hipMemsetAsync(inv_out, 0, 800000, stream);
    deg_kernel<<<(E + 255) / 256, 256, 0, stream>>>(src, dst, inv_out, inv_in, E);
    rsqrt_kernel<<<(N_NODES + 255) / 256, 256, 0, stream>>>(inv_out, inv_in, N_NODES);

    // Layer 1: aggregate(x * inv_out) then transform (in=128 <= out=256)
    hipMemsetAsync(bufA, 0, (size_t)N_NODES * 128 * 4, stream);
    {
        long long T = (long long)E * 32;
        agg_kernel<128><<<(int)((T + 255) / 256), 256, 0, stream>>>(x, inv_out, src, dst, bufA, E);
    }
    // h1 = relu(agg1 @ W1 * inv_in + b1) -> bufB  [M=100000, K=128, N=256]
    {
        dim3 g((256 + BN - 1) / BN, (N_NODES + BM - 1) / BM);
        sgemm_kernel<<<g, 256, 0, stream>>>(bufA, W1, bufB, N_NODES, 256, 128,
                                            nullptr, inv_in, b1, 1);
    }

    // Layer 2: transform first (in=256 > out=128)
    // t2 = (h1 * inv_out) @ W2 -> bufA  [K=256, N=128]
    {
        dim3 g((128 + BN - 1) / BN, (N_NODES + BM - 1) / BM);
        sgemm_kernel<<<g, 256, 0, stream>>>(bufB, W2, bufA, N_NODES, 128, 256,
                                            inv_out, nullptr, nullptr, 0);
    }
    // agg2 = segment_sum(t2[src] -> dst) -> bufB (reuse), then h2 = relu(agg2*inv_in + b2)
    hipMemsetAsync(bufB, 0, (size_t)N_NODES * 128 * 4, stream);
    {
        long long T = (long long)E * 32;
        agg_kernel<128><<<(int)((T + 255) / 256), 256, 0, stream>>>(bufA, nullptr, src, dst, bufB, E);
    }
    {
        long long T = (long long)N_NODES * 32;
        scale_bias_kernel<128><<<(int)((T + 255) / 256), 256, 0, stream>>>(bufB, inv_in, b2, 1);
    }

    // Layer 3: transform first (in=128 > out=40)
    // t3 = (h2 * inv_out) @ W3 -> bufA  [K=128, N=40]
    {
        dim3 g(1, (N_NODES + BM - 1) / BM);
        sgemm_kernel<<<g, 256, 0, stream>>>(bufB, W3, bufA, N_NODES, 40, 128,
                                            inv_out, nullptr, nullptr, 0);
    }
    // out = segment_sum(t3[src] -> dst) * inv_in + b3
    hipMemsetAsync(out, 0, (size_t)N_NODES * 40 * 4, stream);
    {
        long long T = (long long)E * 10;
        agg_kernel<40><<<(int)((T + 255) / 256), 256, 0, stream>>>(bufA, nullptr, src, dst, out, E);
    }
    {
        long long T = (long long)N_NODES * 10;
        scale_bias_kernel<40><<<(int)((T + 255) / 256), 256, 0, stream>>>(out, inv_in, b3, 0);
    }
}

// Round 2
// 826.617 us; speedup vs baseline: 4.4189x; 4.4189x over previous
//
#include <hip/hip_runtime.h>

#define N_NODES 100000
#define BM 64
#define BN 64
#define BK 32

// ---------------- CSR build ----------------

__global__ void count_kernel(const int* __restrict__ src, const int* __restrict__ dst,
                             int* __restrict__ ocnt, int* __restrict__ icnt, int E) {
    int e = blockIdx.x * blockDim.x + threadIdx.x;
    if (e < E) {
        atomicAdd(&ocnt[src[e]], 1);
        atomicAdd(&icnt[dst[e]], 1);
    }
}

// Single-block exclusive scan of icnt -> rowptr[0..n], copy into cursor.
__global__ __launch_bounds__(1024) void scan_kernel(const int* __restrict__ cnt,
                                                    int* __restrict__ rowptr,
                                                    int* __restrict__ cursor, int n) {
    __shared__ int part[1024];
    int tid = threadIdx.x;
    int per = (n + 1023) / 1024;
    int beg = tid * per;
    int end = min(beg + per, n);
    int sum = 0;
    for (int i = beg; i < end; ++i) sum += cnt[i];
    part[tid] = sum;
    __syncthreads();
    for (int off = 1; off < 1024; off <<= 1) {
        int v = (tid >= off) ? part[tid - off] : 0;
        __syncthreads();
        part[tid] += v;
        __syncthreads();
    }
    int run = part[tid] - sum;  // exclusive prefix
    for (int i = beg; i < end; ++i) {
        rowptr[i] = run;
        cursor[i] = run;
        run += cnt[i];
    }
    if (tid == 1023) rowptr[n] = part[1023];
}

// In-place: reinterpret counts as inv-sqrt norms. Runs AFTER scan (which reads icnt).
__global__ void norm_kernel(int* __restrict__ ocnt, int* __restrict__ icnt, int n) {
    int i = blockIdx.x * blockDim.x + threadIdx.x;
    if (i < n) {
        float o = (float)max(ocnt[i], 1);
        float in = (float)max(icnt[i], 1);
        ((float*)ocnt)[i] = rsqrtf(o);
        ((float*)icnt)[i] = rsqrtf(in);
    }
}

__global__ void fill_kernel(const int* __restrict__ src, const int* __restrict__ dst,
                            int* __restrict__ cursor, int* __restrict__ eidx, int E) {
    int e = blockIdx.x * blockDim.x + threadIdx.x;
    if (e < E) {
        int pos = atomicAdd(&cursor[dst[e]], 1);
        eidx[pos] = src[e];
    }
}

// ---------------- gather aggregation (no atomics) ----------------
// out[n,:] = (relu?)( postScale[n] * sum_{e: dst=n} preScale[src] * x[src,:] + bias )
// One thread per (node, float4-chunk).

template <int F>
__global__ void gather_agg(const float* __restrict__ x, const float* __restrict__ preScale,
                           const int* __restrict__ rowptr, const int* __restrict__ eidx,
                           float* __restrict__ out, const float* __restrict__ postScale,
                           const float* __restrict__ bias, int doRelu) {
    constexpr int V = F / 4;
    int t = blockIdx.x * blockDim.x + threadIdx.x;
    int n = t / V;
    int v = t - n * V;
    if (n >= N_NODES) return;
    int beg = rowptr[n], end = rowptr[n + 1];
    float ax = 0.f, ay = 0.f, az = 0.f, aw = 0.f;
    for (int j = beg; j < end; ++j) {
        int s = eidx[j];
        float sc = preScale ? preScale[s] : 1.0f;
        float4 val = ((const float4*)x)[(size_t)s * V + v];
        ax = fmaf(val.x, sc, ax);
        ay = fmaf(val.y, sc, ay);
        az = fmaf(val.z, sc, az);
        aw = fmaf(val.w, sc, aw);
    }
    float ps = postScale ? postScale[n] : 1.0f;
    ax *= ps; ay *= ps; az *= ps; aw *= ps;
    if (bias) {
        float4 b = ((const float4*)bias)[v];
        ax += b.x; ay += b.y; az += b.z; aw += b.w;
    }
    if (doRelu) {
        ax = fmaxf(ax, 0.f); ay = fmaxf(ay, 0.f);
        az = fmaxf(az, 0.f); aw = fmaxf(aw, 0.f);
    }
    float4 o = make_float4(ax, ay, az, aw);
    ((float4*)out)[(size_t)n * V + v] = o;
}

// ---------------- fp32 tiled GEMM ----------------
// C[M,N] = (preScale ? diag(preScale) : I) * A[M,K] @ B[K,N], then
// epilogue: * postScale[row] + bias[col], optional relu.

__global__ __launch_bounds__(256) void sgemm_kernel(
    const float* __restrict__ A, const float* __restrict__ B, float* __restrict__ C,
    int M, int N, int K,
    const float* __restrict__ preScale, const float* __restrict__ postScale,
    const float* __restrict__ bias, int doRelu) {
    __shared__ float As[BK][BM + 4];
    __shared__ float Bs[BK][BN + 4];

    const int tid = threadIdx.x;
    const int tx = tid & 15;
    const int ty = tid >> 4;
    const int rowBase = blockIdx.y * BM;
    const int colBase = blockIdx.x * BN;

    float acc[4][4] = {{0.0f}};

    for (int k0 = 0; k0 < K; k0 += BK) {
#pragma unroll
        for (int i = 0; i < 2; ++i) {
            int idx = tid + i * 256;
            int r = idx >> 3;
            int c4 = idx & 7;
            int gr = rowBase + r;
            float4 v = make_float4(0.f, 0.f, 0.f, 0.f);
            if (gr < M) {
                v = *(const float4*)(A + (size_t)gr * K + k0 + c4 * 4);
                if (preScale) {
                    float s = preScale[gr];
                    v.x *= s; v.y *= s; v.z *= s; v.w *= s;
                }
            }
            As[c4 * 4 + 0][r] = v.x;
            As[c4 * 4 + 1][r] = v.y;
            As[c4 * 4 + 2][r] = v.z;
            As[c4 * 4 + 3][r] = v.w;
        }
#pragma unroll
        for (int i = 0; i < 2; ++i) {
            int idx = tid + i * 256;
            int r = idx >> 4;
            int c4 = idx & 15;
            int gc = colBase + c4 * 4;
            float4 v = make_float4(0.f, 0.f, 0.f, 0.f);
            if (gc < N) v = *(const float4*)(B + (size_t)(k0 + r) * N + gc);
            *(float4*)&Bs[r][c4 * 4] = v;
        }
        __syncthreads();
#pragma unroll
        for (int k = 0; k < BK; ++k) {
            float4 av = *(const float4*)&As[k][ty * 4];
            float4 bv = *(const float4*)&Bs[k][tx * 4];
            float a[4] = {av.x, av.y, av.z, av.w};
            float b[4] = {bv.x, bv.y, bv.z, bv.w};
#pragma unroll
            for (int i = 0; i < 4; ++i)
#pragma unroll
                for (int j = 0; j < 4; ++j)
                    acc[i][j] = fmaf(a[i], b[j], acc[i][j]);
        }
        __syncthreads();
    }

    int gc = colBase + tx * 4;
    if (gc >= N) return;
#pragma unroll
    for (int i = 0; i < 4; ++i) {
        int gr = rowBase + ty * 4 + i;
        if (gr >= M) continue;
        float ps = postScale ? postScale[gr] : 1.0f;
        float4 o;
        o.x = acc[i][0] * ps;
        o.y = acc[i][1] * ps;
        o.z = acc[i][2] * ps;
        o.w = acc[i][3] * ps;
        if (bias) {
            o.x += bias[gc + 0];
            o.y += bias[gc + 1];
            o.z += bias[gc + 2];
            o.w += bias[gc + 3];
        }
        if (doRelu) {
            o.x = fmaxf(o.x, 0.0f);
            o.y = fmaxf(o.y, 0.0f);
            o.z = fmaxf(o.z, 0.0f);
            o.w = fmaxf(o.w, 0.0f);
        }
        *(float4*)(C + (size_t)gr * N + gc) = o;
    }
}

// ---------------- launch ----------------

extern "C" void kernel_launch(void* const* d_in, const int* in_sizes, int n_in,
                              void* d_out, int out_size, void* d_ws, size_t ws_size,
                              hipStream_t stream) {
    const float* x  = (const float*)d_in[0];
    const int* src  = (const int*)d_in[1];
    const int* dst  = (const int*)d_in[2];
    const float* W1 = (const float*)d_in[3];
    const float* b1 = (const float*)d_in[4];
    const float* W2 = (const float*)d_in[5];
    const float* b2 = (const float*)d_in[6];
    const float* W3 = (const float*)d_in[7];
    const float* b3 = (const float*)d_in[8];
    float* out = (float*)d_out;
    const int E = in_sizes[1];

    char* ws = (char*)d_ws;
    int* ocnt     = (int*)ws;                         // 100000 (becomes inv_out f32)
    int* icnt     = (int*)(ws + 400000);              // 100000 (becomes inv_in f32)
    int* rowptr   = (int*)(ws + 800000);              // 100001
    int* cursor   = (int*)(ws + 1200128);             // 100000
    int* eidx     = (int*)(ws + 1600128);             // 800000 (3.2 MB)
    float* bufA   = (float*)(ws + 4800128);           // 100000*128 f32 (51.2 MB)
    float* bufB   = (float*)(ws + 56000128);          // 100000*256 f32 (102.4 MB)
    const float* inv_out = (const float*)ocnt;
    const float* inv_in  = (const float*)icnt;

    // ---- CSR build + norms ----
    hipMemsetAsync(ocnt, 0, 800000, stream);  // zeros ocnt+icnt (contiguous)
    count_kernel<<<(E + 255) / 256, 256, 0, stream>>>(src, dst, ocnt, icnt, E);
    scan_kernel<<<1, 1024, 0, stream>>>(icnt, rowptr, cursor, N_NODES);
    norm_kernel<<<(N_NODES + 255) / 256, 256, 0, stream>>>(ocnt, icnt, N_NODES);
    fill_kernel<<<(E + 255) / 256, 256, 0, stream>>>(src, dst, cursor, eidx, E);

    // ---- Layer 1: aggregate(x * inv_out) then transform (in=128 <= out=256) ----
    {
        long long T = (long long)N_NODES * 32;
        gather_agg<128><<<(int)((T + 255) / 256), 256, 0, stream>>>(
            x, inv_out, rowptr, eidx, bufA, nullptr, nullptr, 0);
    }
    // h1 = relu(agg1 @ W1 * inv_in + b1) -> bufB  [M=100000, K=128, N=256]
    {
        dim3 g((256 + BN - 1) / BN, (N_NODES + BM - 1) / BM);
        sgemm_kernel<<<g, 256, 0, stream>>>(bufA, W1, bufB, N_NODES, 256, 128,
                                            nullptr, inv_in, b1, 1);
    }

    // ---- Layer 2: transform first (in=256 > out=128) ----
    // t2 = (h1 * inv_out) @ W2 -> bufA  [K=256, N=128]
    {
        dim3 g((128 + BN - 1) / BN, (N_NODES + BM - 1) / BM);
        sgemm_kernel<<<g, 256, 0, stream>>>(bufB, W2, bufA, N_NODES, 128, 256,
                                            inv_out, nullptr, nullptr, 0);
    }
    // h2 = relu(segsum(t2) * inv_in + b2) -> bufB (epilogue fused into gather)
    {
        long long T = (long long)N_NODES * 32;
        gather_agg<128><<<(int)((T + 255) / 256), 256, 0, stream>>>(
            bufA, nullptr, rowptr, eidx, bufB, inv_in, b2, 1);
    }

    // ---- Layer 3: transform first (in=128 > out=40) ----
    // t3 = (h2 * inv_out) @ W3 -> bufA  [K=128, N=40]
    {
        dim3 g(1, (N_NODES + BM - 1) / BM);
        sgemm_kernel<<<g, 256, 0, stream>>>(bufB, W3, bufA, N_NODES, 40, 128,
                                            inv_out, nullptr, nullptr, 0);
    }
    // out = segsum(t3) * inv_in + b3 (epilogue fused into gather)
    {
        long long T = (long long)N_NODES * 10;
        gather_agg<40><<<(int)((T + 255) / 256), 256, 0, stream>>>(
            bufA, nullptr, rowptr, eidx, out, inv_in, b3, 0);
    }
}

// Round 3
// 610.385 us; speedup vs baseline: 5.9843x; 1.3543x over previous
//
#include <hip/hip_runtime.h>

#define N_NODES 100000
#define BM 64
#define BN 64
#define BK 32
#define SCAN_NB 128
#define SCAN_TPB 256

// ---------------- CSR build ----------------

__global__ void count_kernel(const int* __restrict__ src, const int* __restrict__ dst,
                             int* __restrict__ ocnt, int* __restrict__ icnt, int E) {
    int e = blockIdx.x * blockDim.x + threadIdx.x;
    if (e < E) {
        atomicAdd(&ocnt[src[e]], 1);
        atomicAdd(&icnt[dst[e]], 1);
    }
}

// Phase 1: per-block chunk sums.
__global__ __launch_bounds__(SCAN_TPB) void scan_reduce(const int* __restrict__ cnt,
                                                        int* __restrict__ blockSum, int n) {
    __shared__ int s[SCAN_TPB];
    int chunk = (n + SCAN_NB - 1) / SCAN_NB;
    int beg = blockIdx.x * chunk;
    int end = min(beg + chunk, n);
    int sum = 0;
    for (int i = beg + threadIdx.x; i < end; i += SCAN_TPB) sum += cnt[i];
    s[threadIdx.x] = sum;
    __syncthreads();
    for (int off = SCAN_TPB / 2; off > 0; off >>= 1) {
        if (threadIdx.x < off) s[threadIdx.x] += s[threadIdx.x + off];
        __syncthreads();
    }
    if (threadIdx.x == 0) blockSum[blockIdx.x] = s[0];
}

// Phase 2: exclusive scan of the SCAN_NB block sums (in place); total -> rowptr[n].
__global__ __launch_bounds__(SCAN_NB) void scan_offsets(int* __restrict__ blockSum,
                                                        int* __restrict__ rowptr_total) {
    __shared__ int s[SCAN_NB];
    int tid = threadIdx.x;
    int v = blockSum[tid];
    s[tid] = v;
    __syncthreads();
    for (int off = 1; off < SCAN_NB; off <<= 1) {
        int t = (tid >= off) ? s[tid - off] : 0;
        __syncthreads();
        s[tid] += t;
        __syncthreads();
    }
    blockSum[tid] = s[tid] - v;  // exclusive
    if (tid == SCAN_NB - 1) rowptr_total[0] = s[tid];
}

// Phase 3: in-chunk scan + block offset -> rowptr, cursor.
__global__ __launch_bounds__(SCAN_TPB) void scan_final(const int* __restrict__ cnt,
                                                       const int* __restrict__ blockSum,
                                                       int* __restrict__ rowptr,
                                                       int* __restrict__ cursor, int n) {
    __shared__ int s[SCAN_TPB];
    int chunk = (n + SCAN_NB - 1) / SCAN_NB;
    int beg = blockIdx.x * chunk;
    int end = min(beg + chunk, n);
    int carry = blockSum[blockIdx.x];
    for (int base = beg; base < end; base += SCAN_TPB) {
        int i = base + threadIdx.x;
        int v = (i < end) ? cnt[i] : 0;
        s[threadIdx.x] = v;
        __syncthreads();
        for (int off = 1; off < SCAN_TPB; off <<= 1) {
            int t = (threadIdx.x >= off) ? s[threadIdx.x - off] : 0;
            __syncthreads();
            s[threadIdx.x] += t;
            __syncthreads();
        }
        int excl = s[threadIdx.x] - v;
        if (i < end) {
            rowptr[i] = carry + excl;
            cursor[i] = carry + excl;
        }
        int roundSum = s[SCAN_TPB - 1];
        __syncthreads();  // all reads of s done before next round overwrites
        carry += roundSum;
    }
}

// In-place: reinterpret counts as inv-sqrt norms. Runs AFTER the scan reads icnt.
__global__ void norm_kernel(int* __restrict__ ocnt, int* __restrict__ icnt, int n) {
    int i = blockIdx.x * blockDim.x + threadIdx.x;
    if (i < n) {
        float o = (float)max(ocnt[i], 1);
        float in = (float)max(icnt[i], 1);
        ((float*)ocnt)[i] = rsqrtf(o);
        ((float*)icnt)[i] = rsqrtf(in);
    }
}

__global__ void fill_kernel(const int* __restrict__ src, const int* __restrict__ dst,
                            int* __restrict__ cursor, int* __restrict__ eidx, int E) {
    int e = blockIdx.x * blockDim.x + threadIdx.x;
    if (e < E) {
        int pos = atomicAdd(&cursor[dst[e]], 1);
        eidx[pos] = src[e];
    }
}

// ---------------- gather aggregation (no atomics) ----------------
// out[n,:] = (relu?)( postScale[n] * sum_{e: dst=n} preScale[src] * x[src,:] + bias )
// One thread per (node, float4-chunk).

template <int F>
__global__ void gather_agg(const float* __restrict__ x, const float* __restrict__ preScale,
                           const int* __restrict__ rowptr, const int* __restrict__ eidx,
                           float* __restrict__ out, const float* __restrict__ postScale,
                           const float* __restrict__ bias, int doRelu) {
    constexpr int V = F / 4;
    int t = blockIdx.x * blockDim.x + threadIdx.x;
    int n = t / V;
    int v = t - n * V;
    if (n >= N_NODES) return;
    int beg = rowptr[n], end = rowptr[n + 1];
    float ax = 0.f, ay = 0.f, az = 0.f, aw = 0.f;
    for (int j = beg; j < end; ++j) {
        int s = eidx[j];
        float sc = preScale ? preScale[s] : 1.0f;
        float4 val = ((const float4*)x)[(size_t)s * V + v];
        ax = fmaf(val.x, sc, ax);
        ay = fmaf(val.y, sc, ay);
        az = fmaf(val.z, sc, az);
        aw = fmaf(val.w, sc, aw);
    }
    float ps = postScale ? postScale[n] : 1.0f;
    ax *= ps; ay *= ps; az *= ps; aw *= ps;
    if (bias) {
        float4 b = ((const float4*)bias)[v];
        ax += b.x; ay += b.y; az += b.z; aw += b.w;
    }
    if (doRelu) {
        ax = fmaxf(ax, 0.f); ay = fmaxf(ay, 0.f);
        az = fmaxf(az, 0.f); aw = fmaxf(aw, 0.f);
    }
    float4 o = make_float4(ax, ay, az, aw);
    ((float4*)out)[(size_t)n * V + v] = o;
}

// ---------------- fp32 tiled GEMM ----------------
// C[M,N] = (preScale ? diag(preScale) : I) * A[M,K] @ B[K,N], then
// epilogue: * postScale[row] + bias[col], optional relu.

__global__ __launch_bounds__(256) void sgemm_kernel(
    const float* __restrict__ A, const float* __restrict__ B, float* __restrict__ C,
    int M, int N, int K,
    const float* __restrict__ preScale, const float* __restrict__ postScale,
    const float* __restrict__ bias, int doRelu) {
    __shared__ float As[BK][BM + 4];
    __shared__ float Bs[BK][BN + 4];

    const int tid = threadIdx.x;
    const int tx = tid & 15;
    const int ty = tid >> 4;
    const int rowBase = blockIdx.y * BM;
    const int colBase = blockIdx.x * BN;

    float acc[4][4] = {{0.0f}};

    for (int k0 = 0; k0 < K; k0 += BK) {
#pragma unroll
        for (int i = 0; i < 2; ++i) {
            int idx = tid + i * 256;
            int r = idx >> 3;
            int c4 = idx & 7;
            int gr = rowBase + r;
            float4 v = make_float4(0.f, 0.f, 0.f, 0.f);
            if (gr < M) {
                v = *(const float4*)(A + (size_t)gr * K + k0 + c4 * 4);
                if (preScale) {
                    float s = preScale[gr];
                    v.x *= s; v.y *= s; v.z *= s; v.w *= s;
                }
            }
            As[c4 * 4 + 0][r] = v.x;
            As[c4 * 4 + 1][r] = v.y;
            As[c4 * 4 + 2][r] = v.z;
            As[c4 * 4 + 3][r] = v.w;
        }
#pragma unroll
        for (int i = 0; i < 2; ++i) {
            int idx = tid + i * 256;
            int r = idx >> 4;
            int c4 = idx & 15;
            int gc = colBase + c4 * 4;
            float4 v = make_float4(0.f, 0.f, 0.f, 0.f);
            if (gc < N) v = *(const float4*)(B + (size_t)(k0 + r) * N + gc);
            *(float4*)&Bs[r][c4 * 4] = v;
        }
        __syncthreads();
#pragma unroll
        for (int k = 0; k < BK; ++k) {
            float4 av = *(const float4*)&As[k][ty * 4];
            float4 bv = *(const float4*)&Bs[k][tx * 4];
            float a[4] = {av.x, av.y, av.z, av.w};
            float b[4] = {bv.x, bv.y, bv.z, bv.w};
#pragma unroll
            for (int i = 0; i < 4; ++i)
#pragma unroll
                for (int j = 0; j < 4; ++j)
                    acc[i][j] = fmaf(a[i], b[j], acc[i][j]);
        }
        __syncthreads();
    }

    int gc = colBase + tx * 4;
    if (gc >= N) return;
#pragma unroll
    for (int i = 0; i < 4; ++i) {
        int gr = rowBase + ty * 4 + i;
        if (gr >= M) continue;
        float ps = postScale ? postScale[gr] : 1.0f;
        float4 o;
        o.x = acc[i][0] * ps;
        o.y = acc[i][1] * ps;
        o.z = acc[i][2] * ps;
        o.w = acc[i][3] * ps;
        if (bias) {
            o.x += bias[gc + 0];
            o.y += bias[gc + 1];
            o.z += bias[gc + 2];
            o.w += bias[gc + 3];
        }
        if (doRelu) {
            o.x = fmaxf(o.x, 0.0f);
            o.y = fmaxf(o.y, 0.0f);
            o.z = fmaxf(o.z, 0.0f);
            o.w = fmaxf(o.w, 0.0f);
        }
        *(float4*)(C + (size_t)gr * N + gc) = o;
    }
}

// ---------------- launch ----------------

extern "C" void kernel_launch(void* const* d_in, const int* in_sizes, int n_in,
                              void* d_out, int out_size, void* d_ws, size_t ws_size,
                              hipStream_t stream) {
    const float* x  = (const float*)d_in[0];
    const int* src  = (const int*)d_in[1];
    const int* dst  = (const int*)d_in[2];
    const float* W1 = (const float*)d_in[3];
    const float* b1 = (const float*)d_in[4];
    const float* W2 = (const float*)d_in[5];
    const float* b2 = (const float*)d_in[6];
    const float* W3 = (const float*)d_in[7];
    const float* b3 = (const float*)d_in[8];
    float* out = (float*)d_out;
    const int E = in_sizes[1];

    char* ws = (char*)d_ws;
    int* ocnt     = (int*)ws;                         // 100000 (becomes inv_out f32)
    int* icnt     = (int*)(ws + 400000);              // 100000 (becomes inv_in f32)
    int* rowptr   = (int*)(ws + 800000);              // 100001
    int* cursor   = (int*)(ws + 1200128);             // 100000
    int* eidx     = (int*)(ws + 1600128);             // 800000 (3.2 MB)
    int* blockSum = (int*)(ws + 4800128);             // SCAN_NB
    float* bufA   = (float*)(ws + 4801152);           // 100000*128 f32 (51.2 MB)
    float* bufB   = (float*)(ws + 56001152);          // 100000*256 f32 (102.4 MB)
    const float* inv_out = (const float*)ocnt;
    const float* inv_in  = (const float*)icnt;

    // ---- CSR build + norms ----
    hipMemsetAsync(ocnt, 0, 800000, stream);  // zeros ocnt+icnt (contiguous)
    count_kernel<<<(E + 255) / 256, 256, 0, stream>>>(src, dst, ocnt, icnt, E);
    scan_reduce<<<SCAN_NB, SCAN_TPB, 0, stream>>>(icnt, blockSum, N_NODES);
    scan_offsets<<<1, SCAN_NB, 0, stream>>>(blockSum, rowptr + N_NODES);
    scan_final<<<SCAN_NB, SCAN_TPB, 0, stream>>>(icnt, blockSum, rowptr, cursor, N_NODES);
    norm_kernel<<<(N_NODES + 255) / 256, 256, 0, stream>>>(ocnt, icnt, N_NODES);
    fill_kernel<<<(E + 255) / 256, 256, 0, stream>>>(src, dst, cursor, eidx, E);

    // ---- Layer 1: aggregate(x * inv_out) then transform (in=128 <= out=256) ----
    {
        long long T = (long long)N_NODES * 32;
        gather_agg<128><<<(int)((T + 255) / 256), 256, 0, stream>>>(
            x, inv_out, rowptr, eidx, bufA, nullptr, nullptr, 0);
    }
    // h1 = relu(agg1 @ W1 * inv_in + b1) -> bufB  [M=100000, K=128, N=256]
    {
        dim3 g((256 + BN - 1) / BN, (N_NODES + BM - 1) / BM);
        sgemm_kernel<<<g, 256, 0, stream>>>(bufA, W1, bufB, N_NODES, 256, 128,
                                            nullptr, inv_in, b1, 1);
    }

    // ---- Layer 2: transform first (in=256 > out=128) ----
    // t2 = (h1 * inv_out) @ W2 -> bufA  [K=256, N=128]
    {
        dim3 g((128 + BN - 1) / BN, (N_NODES + BM - 1) / BM);
        sgemm_kernel<<<g, 256, 0, stream>>>(bufB, W2, bufA, N_NODES, 128, 256,
                                            inv_out, nullptr, nullptr, 0);
    }
    // h2 = relu(segsum(t2) * inv_in + b2) -> bufB (epilogue fused into gather)
    {
        long long T = (long long)N_NODES * 32;
        gather_agg<128><<<(int)((T + 255) / 256), 256, 0, stream>>>(
            bufA, nullptr, rowptr, eidx, bufB, inv_in, b2, 1);
    }

    // ---- Layer 3: transform first (in=128 > out=40) ----
    // t3 = (h2 * inv_out) @ W3 -> bufA  [K=128, N=40]
    {
        dim3 g(1, (N_NODES + BM - 1) / BM);
        sgemm_kernel<<<g, 256, 0, stream>>>(bufB, W3, bufA, N_NODES, 40, 128,
                                            inv_out, nullptr, nullptr, 0);
    }
    // out = segsum(t3) * inv_in + b3 (epilogue fused into gather)
    {
        long long T = (long long)N_NODES * 10;
        gather_agg<40><<<(int)((T + 255) / 256), 256, 0, stream>>>(
            bufA, nullptr, rowptr, eidx, out, inv_in, b3, 0);
    }
}

// Round 4
// 445.617 us; speedup vs baseline: 8.1970x; 1.3698x over previous
//
#include <hip/hip_runtime.h>

#define N_NODES 100000
#define SCAN_NB 128
#define SCAN_TPB 256

typedef _Float16 half_t;
typedef __attribute__((ext_vector_type(8))) _Float16 v8h;
typedef __attribute__((ext_vector_type(4))) _Float16 v4h;
typedef __attribute__((ext_vector_type(4))) float v4f;

// ---------------- CSR build ----------------

__global__ void count_kernel(const int* __restrict__ src, const int* __restrict__ dst,
                             int* __restrict__ ocnt, int* __restrict__ icnt, int E) {
    int e = blockIdx.x * blockDim.x + threadIdx.x;
    if (e < E) {
        atomicAdd(&ocnt[src[e]], 1);
        atomicAdd(&icnt[dst[e]], 1);
    }
}

__global__ __launch_bounds__(SCAN_TPB) void scan_reduce(const int* __restrict__ cnt,
                                                        int* __restrict__ blockSum, int n) {
    __shared__ int s[SCAN_TPB];
    int chunk = (n + SCAN_NB - 1) / SCAN_NB;
    int beg = blockIdx.x * chunk;
    int end = min(beg + chunk, n);
    int sum = 0;
    for (int i = beg + threadIdx.x; i < end; i += SCAN_TPB) sum += cnt[i];
    s[threadIdx.x] = sum;
    __syncthreads();
    for (int off = SCAN_TPB / 2; off > 0; off >>= 1) {
        if (threadIdx.x < off) s[threadIdx.x] += s[threadIdx.x + off];
        __syncthreads();
    }
    if (threadIdx.x == 0) blockSum[blockIdx.x] = s[0];
}

__global__ __launch_bounds__(SCAN_NB) void scan_offsets(int* __restrict__ blockSum,
                                                        int* __restrict__ rowptr_total) {
    __shared__ int s[SCAN_NB];
    int tid = threadIdx.x;
    int v = blockSum[tid];
    s[tid] = v;
    __syncthreads();
    for (int off = 1; off < SCAN_NB; off <<= 1) {
        int t = (tid >= off) ? s[tid - off] : 0;
        __syncthreads();
        s[tid] += t;
        __syncthreads();
    }
    blockSum[tid] = s[tid] - v;
    if (tid == SCAN_NB - 1) rowptr_total[0] = s[tid];
}

__global__ __launch_bounds__(SCAN_TPB) void scan_final(const int* __restrict__ cnt,
                                                       const int* __restrict__ blockSum,
                                                       int* __restrict__ rowptr,
                                                       int* __restrict__ cursor, int n) {
    __shared__ int s[SCAN_TPB];
    int chunk = (n + SCAN_NB - 1) / SCAN_NB;
    int beg = blockIdx.x * chunk;
    int end = min(beg + chunk, n);
    int carry = blockSum[blockIdx.x];
    for (int base = beg; base < end; base += SCAN_TPB) {
        int i = base + threadIdx.x;
        int v = (i < end) ? cnt[i] : 0;
        s[threadIdx.x] = v;
        __syncthreads();
        for (int off = 1; off < SCAN_TPB; off <<= 1) {
            int t = (threadIdx.x >= off) ? s[threadIdx.x - off] : 0;
            __syncthreads();
            s[threadIdx.x] += t;
            __syncthreads();
        }
        int excl = s[threadIdx.x] - v;
        if (i < end) {
            rowptr[i] = carry + excl;
            cursor[i] = carry + excl;
        }
        int roundSum = s[SCAN_TPB - 1];
        __syncthreads();
        carry += roundSum;
    }
}

__global__ void norm_kernel(int* __restrict__ ocnt, int* __restrict__ icnt, int n) {
    int i = blockIdx.x * blockDim.x + threadIdx.x;
    if (i < n) {
        float o = (float)max(ocnt[i], 1);
        float in = (float)max(icnt[i], 1);
        ((float*)ocnt)[i] = rsqrtf(o);
        ((float*)icnt)[i] = rsqrtf(in);
    }
}

__global__ void fill_kernel(const int* __restrict__ src, const int* __restrict__ dst,
                            int* __restrict__ cursor, int* __restrict__ eidx, int E) {
    int e = blockIdx.x * blockDim.x + threadIdx.x;
    if (e < E) {
        int pos = atomicAdd(&cursor[dst[e]], 1);
        eidx[pos] = src[e];
    }
}

// ---------------- conversions ----------------

// xh[n][:] = (half)(x[n][:] * invOut[n]); one thread per float4 chunk.
__global__ void conv_x(const float* __restrict__ x, const float* __restrict__ invOut,
                       half_t* __restrict__ xh) {
    int t = blockIdx.x * blockDim.x + threadIdx.x;  // N_NODES*32 chunks
    int n = t >> 5;
    if (n >= N_NODES) return;
    float4 v = ((const float4*)x)[t];
    float s = invOut[n];
    v4h h;
    h[0] = (half_t)(v.x * s);
    h[1] = (half_t)(v.y * s);
    h[2] = (half_t)(v.z * s);
    h[3] = (half_t)(v.w * s);
    *(v4h*)(xh + (size_t)t * 4) = h;
}

// Wt[n][k] = (half) W[k][n]
__global__ void convT_w(const float* __restrict__ W, half_t* __restrict__ Wt, int K, int N) {
    int t = blockIdx.x * blockDim.x + threadIdx.x;
    if (t >= K * N) return;
    int n = t / K;
    int k = t - n * K;
    Wt[t] = (half_t)W[(size_t)k * N + n];
}

// ---------------- gather aggregation (fp16 rows, fp32 accum) ----------------
// MODE 0: out fp16 = sum
// MODE 1: out fp16 = max((sum*invIn[n]+bias)*invOut[n], 0)
// MODE 2: out fp32 = sum*invIn[n]+bias

template <int F, int MODE>
__global__ void gather_h(const half_t* __restrict__ x,
                         const int* __restrict__ rowptr, const int* __restrict__ eidx,
                         void* __restrict__ outv,
                         const float* __restrict__ invIn, const float* __restrict__ invOut,
                         const float* __restrict__ bias) {
    constexpr int V = F / 8;
    int t = blockIdx.x * blockDim.x + threadIdx.x;
    int n = t / V;
    int v = t - n * V;
    if (n >= N_NODES) return;
    int beg = rowptr[n], end = rowptr[n + 1];
    float acc[8] = {};
    for (int j = beg; j < end; ++j) {
        int s = eidx[j];
        v8h val = *(const v8h*)(x + (size_t)s * F + v * 8);
#pragma unroll
        for (int q = 0; q < 8; ++q) acc[q] += (float)val[q];
    }
    if (MODE == 0) {
        v8h o;
#pragma unroll
        for (int q = 0; q < 8; ++q) o[q] = (half_t)acc[q];
        *(v8h*)((half_t*)outv + (size_t)n * F + v * 8) = o;
    } else if (MODE == 1) {
        float ii = invIn[n], io = invOut[n];
        v8h o;
#pragma unroll
        for (int q = 0; q < 8; ++q)
            o[q] = (half_t)fmaxf((acc[q] * ii + bias[v * 8 + q]) * io, 0.f);
        *(v8h*)((half_t*)outv + (size_t)n * F + v * 8) = o;
    } else {
        float ii = invIn[n];
        float* o = (float*)outv + (size_t)n * F + v * 8;
#pragma unroll
        for (int q = 0; q < 8; ++q) o[q] = acc[q] * ii + bias[v * 8 + q];
    }
}

// ---------------- f16 MFMA GEMM ----------------
// C[M,N] = A[M,K] @ Bt[N,K]^T  (A fp16 row-major, Bt = W^T fp16)
// mode 0: Ch = (half)z ; mode 1: Ch = (half) max((z*invIn[m]+bias[n])*invOut[m], 0)
// Block: 256 thr = 4 waves (2x2), tile 128 x BN_, BK=32.

template <int BN_>
__global__ __launch_bounds__(256) void mfma_gemm(
    const half_t* __restrict__ A, const half_t* __restrict__ Bt,
    half_t* __restrict__ Ch, int M, int N, int K,
    const float* __restrict__ invIn, const float* __restrict__ invOut,
    const float* __restrict__ bias, int mode) {
    constexpr int BM_ = 128, BK_ = 32;
    constexpr int LDA = BK_ + 8;  // 40 halves = 80B rows: bank-start 20n+4q, 2-way max
    __shared__ half_t As[BM_][LDA];
    __shared__ half_t Bs[BN_][LDA];

    const int tid = threadIdx.x;
    const int wave = tid >> 6, lane = tid & 63;
    const int quad = lane >> 4, l16 = lane & 15;
    const int wm = (wave & 1) * 64;       // wave m-offset (4 x 16 tiles)
    constexpr int WN = BN_ / 2;           // wave n-span
    constexpr int NT = WN / 16;           // n-tiles per wave
    const int wn = (wave >> 1) * WN;
    const int mBase = blockIdx.y * BM_;
    const int nBase = blockIdx.x * BN_;

    v4f acc[4][NT] = {};

    for (int k0 = 0; k0 < K; k0 += BK_) {
        // stage A: 128 rows x 32 halves (4 x 16B chunks per row)
#pragma unroll
        for (int i = 0; i < 2; ++i) {
            int idx = tid + i * 256;
            int r = idx >> 2, c = idx & 3;
            int gr = mBase + r;
            float4 v = make_float4(0.f, 0.f, 0.f, 0.f);
            if (gr < M) v = *(const float4*)(A + (size_t)gr * K + k0 + c * 8);
            *(float4*)&As[r][c * 8] = v;
        }
        // stage B: BN_ rows x 32 halves
        constexpr int BL = BN_ * 4 / 256;
#pragma unroll
        for (int i = 0; i < BL; ++i) {
            int idx = tid + i * 256;
            int r = idx >> 2, c = idx & 3;
            int gn = nBase + r;
            float4 v = make_float4(0.f, 0.f, 0.f, 0.f);
            if (gn < N) v = *(const float4*)(Bt + (size_t)gn * K + k0 + c * 8);
            *(float4*)&Bs[r][c * 8] = v;
        }
        __syncthreads();

        v8h a[4], b[NT];
#pragma unroll
        for (int i = 0; i < 4; ++i) a[i] = *(const v8h*)&As[wm + i * 16 + l16][quad * 8];
#pragma unroll
        for (int j = 0; j < NT; ++j) b[j] = *(const v8h*)&Bs[wn + j * 16 + l16][quad * 8];
#pragma unroll
        for (int i = 0; i < 4; ++i)
#pragma unroll
            for (int j = 0; j < NT; ++j)
                acc[i][j] = __builtin_amdgcn_mfma_f32_16x16x32_f16(a[i], b[j], acc[i][j], 0, 0, 0);
        __syncthreads();
    }

    // epilogue: C frag: col = l16, row = quad*4 + reg
#pragma unroll
    for (int i = 0; i < 4; ++i) {
#pragma unroll
        for (int j = 0; j < NT; ++j) {
            int gn = nBase + wn + j * 16 + l16;
            if (gn >= N) continue;
            float bv = (mode == 1) ? bias[gn] : 0.f;
#pragma unroll
            for (int r = 0; r < 4; ++r) {
                int gm = mBase + wm + i * 16 + quad * 4 + r;
                if (gm >= M) continue;
                float z = acc[i][j][r];
                if (mode == 1) z = fmaxf((z * invIn[gm] + bv) * invOut[gm], 0.f);
                Ch[(size_t)gm * N + gn] = (half_t)z;
            }
        }
    }
}

// ---------------- launch ----------------

extern "C" void kernel_launch(void* const* d_in, const int* in_sizes, int n_in,
                              void* d_out, int out_size, void* d_ws, size_t ws_size,
                              hipStream_t stream) {
    const float* x  = (const float*)d_in[0];
    const int* src  = (const int*)d_in[1];
    const int* dst  = (const int*)d_in[2];
    const float* W1 = (const float*)d_in[3];
    const float* b1 = (const float*)d_in[4];
    const float* W2 = (const float*)d_in[5];
    const float* b2 = (const float*)d_in[6];
    const float* W3 = (const float*)d_in[7];
    const float* b3 = (const float*)d_in[8];
    float* out = (float*)d_out;
    const int E = in_sizes[1];

    char* ws = (char*)d_ws;
    int* ocnt     = (int*)ws;                     // 100000 (becomes inv_out f32)
    int* icnt     = (int*)(ws + 400000);          // 100000 (becomes inv_in f32)
    int* rowptr   = (int*)(ws + 800000);          // 100001
    int* cursor   = (int*)(ws + 1200256);         // 100000
    int* eidx     = (int*)(ws + 1600256);         // 800000 (3.2 MB)
    int* blockSum = (int*)(ws + 4800256);         // 128
    half_t* Wt1   = (half_t*)(ws + 4800768);      // 256x128 fp16 (64 KB)
    half_t* Wt2   = (half_t*)(ws + 4866304);      // 128x256 fp16 (64 KB)
    half_t* Wt3   = (half_t*)(ws + 4931840);      // 40x128 fp16 (10 KB)
    half_t* buf0  = (half_t*)(ws + 5000192);      // 25.6 MB: xh, later h2'
    half_t* buf1  = (half_t*)(ws + 30600192);     // 25.6 MB: agg1, later t2
    half_t* buf2  = (half_t*)(ws + 56200192);     // 51.2 MB: h1', later t3
    const float* inv_out = (const float*)ocnt;
    const float* inv_in  = (const float*)icnt;

    // ---- CSR + norms ----
    hipMemsetAsync(ocnt, 0, 800000, stream);
    count_kernel<<<(E + 255) / 256, 256, 0, stream>>>(src, dst, ocnt, icnt, E);
    scan_reduce<<<SCAN_NB, SCAN_TPB, 0, stream>>>(icnt, blockSum, N_NODES);
    scan_offsets<<<1, SCAN_NB, 0, stream>>>(blockSum, rowptr + N_NODES);
    scan_final<<<SCAN_NB, SCAN_TPB, 0, stream>>>(icnt, blockSum, rowptr, cursor, N_NODES);
    norm_kernel<<<(N_NODES + 255) / 256, 256, 0, stream>>>(ocnt, icnt, N_NODES);
    fill_kernel<<<(E + 255) / 256, 256, 0, stream>>>(src, dst, cursor, eidx, E);

    // ---- weight transpose+convert, x convert (x * inv_out -> fp16) ----
    convT_w<<<(128 * 256 + 255) / 256, 256, 0, stream>>>(W1, Wt1, 128, 256);
    convT_w<<<(256 * 128 + 255) / 256, 256, 0, stream>>>(W2, Wt2, 256, 128);
    convT_w<<<(128 * 40 + 255) / 256, 256, 0, stream>>>(W3, Wt3, 128, 40);
    conv_x<<<(N_NODES * 32 + 255) / 256, 256, 0, stream>>>(x, inv_out, buf0);

    // ---- Layer 1: agg1 = segsum(xh) ; h1' = relu((agg1@W1)*inv_in + b1)*inv_out ----
    gather_h<128, 0><<<(N_NODES * 16 + 255) / 256, 256, 0, stream>>>(
        buf0, rowptr, eidx, buf1, nullptr, nullptr, nullptr);
    {
        dim3 g(2, (N_NODES + 127) / 128);
        mfma_gemm<128><<<g, 256, 0, stream>>>(buf1, Wt1, buf2, N_NODES, 256, 128,
                                              inv_in, inv_out, b1, 1);
    }

    // ---- Layer 2: t2 = h1' @ W2 ; h2' = relu((segsum(t2))*inv_in + b2)*inv_out ----
    {
        dim3 g(1, (N_NODES + 127) / 128);
        mfma_gemm<128><<<g, 256, 0, stream>>>(buf2, Wt2, buf1, N_NODES, 128, 256,
                                              nullptr, nullptr, nullptr, 0);
    }
    gather_h<128, 1><<<(N_NODES * 16 + 255) / 256, 256, 0, stream>>>(
        buf1, rowptr, eidx, buf0, inv_in, inv_out, b2);

    // ---- Layer 3: t3 = h2' @ W3 ; out = segsum(t3)*inv_in + b3 ----
    {
        dim3 g(1, (N_NODES + 127) / 128);
        mfma_gemm<64><<<g, 256, 0, stream>>>(buf0, Wt3, buf2, N_NODES, 40, 128,
                                             nullptr, nullptr, nullptr, 0);
    }
    gather_h<40, 2><<<(N_NODES * 5 + 255) / 256, 256, 0, stream>>>(
        buf2, rowptr, eidx, out, inv_in, nullptr, b3);
}